// Round 1
// baseline (122.232 us; speedup 1.0000x reference)
//
#include <hip/hip_runtime.h>
#include <hip/hip_bf16.h>

#define CIN 256
#define NV 4096
#define NHEAD 8
#define HD 32
#define NSPLIT 4
#define KSPAN (NV / NSPLIT)
#define LOG2E 1.44269504088896340736f
#define LOG2_10K_16 0.8304820237218405f  /* log2(10000)/16 */

typedef __attribute__((ext_vector_type(8))) short short8;
typedef __attribute__((ext_vector_type(4))) float f32x4;

static __device__ __forceinline__ unsigned short f2bf(float f) {
    union { float f; unsigned u; } v; v.f = f;
    unsigned r = v.u + 0x7fffu + ((v.u >> 16) & 1u);  // RNE
    return (unsigned short)(r >> 16);
}
// pack two fp32 -> packed bf16 pair (truncating): lo from x0, hi from x1
static __device__ __forceinline__ unsigned pk_bf2(float x0, float x1) {
    return __builtin_amdgcn_perm(__float_as_uint(x1), __float_as_uint(x0),
                                 0x07060302u);
}
static __device__ __forceinline__ float bflo(unsigned u) {
    return __uint_as_float(u << 16);
}
static __device__ __forceinline__ float bfhi(unsigned u) {
    return __uint_as_float(u & 0xffff0000u);
}

// ---------------------------------------------------------------------------
// Kernel 0: convert all weights to bf16 once. Wb = Wq|Wk|Wv|Wo, 327680 elems.
// ---------------------------------------------------------------------------
__global__ __launch_bounds__(256) void conv_w(
    const float* __restrict__ wq, const float* __restrict__ wk,
    const float* __restrict__ wv, const float* __restrict__ wo,
    unsigned short* __restrict__ Wb)
{
    int i = (blockIdx.x * 256 + threadIdx.x) * 4;
    if (i >= 327680) return;
    const float* src;
    int off = i;
    if (i < 65536) { src = wq; }
    else if (i < 131072) { src = wk; off = i - 65536; }
    else if (i < 196608) { src = wv; off = i - 131072; }
    else { src = wo; off = i - 196608; }
    float4 v = *(const float4*)&src[off];
    unsigned short pk[4] = {f2bf(v.x), f2bf(v.y), f2bf(v.z), f2bf(v.w)};
    *(uint2*)&Wb[i] = *(uint2*)pk;
}

// ---------------------------------------------------------------------------
// Kernel 1: QKV projection. 512-thread blocks, N=32 x M=128, grid (128,2,3)
// = 768 blocks (3/CU). x-transpose staged bf16 in LDS once; bf16 MFMA with
// direct Wb fragments; epilogue transposes through LDS -> coalesced stores.
//   Q,K -> [h][n][c] (Q pre-scaled by log2e)
//   V   -> [c][n] with keys PERMUTED within each 32-key half so the attention
//          PV B-fragment is one contiguous 16B LDS read:
//          pos q*8 + g*4 + r  holds key g*16 + q*4 + r   (q,g,r in 4,2,4)
// ---------------------------------------------------------------------------
__global__ __launch_bounds__(512) void qkv_fused(
    const float* __restrict__ x, const unsigned short* __restrict__ Wb,
    const float* __restrict__ bq, const float* __restrict__ bk,
    const float* __restrict__ bv,
    unsigned short* __restrict__ Qbf, unsigned short* __restrict__ Kbf,
    unsigned short* __restrict__ Vbf)
{
    const int which = blockIdx.z;
    const unsigned short* Wp = Wb + (size_t)which * 65536;
    const float* Bp = (which == 0) ? bq : (which == 1) ? bk : bv;
    const int cbase = (which == 0) ? 0 : CIN;

    const int n0 = blockIdx.x * 32;
    const int m0 = blockIdx.y * 128;
    const int t = threadIdx.x;

    __shared__ __align__(16) unsigned short Sbuf[32 * 264];  // 16.9 KB

    // stage x [c][n] fp32 -> Xs[n][c] bf16 (row pitch 264)
    {
        const int n = t & 31, cg = t >> 5;  // 16 groups x 16 channels
#pragma unroll 4
        for (int cc = 0; cc < 16; cc += 2) {
            const int c = cg * 16 + cc;
            size_t off = (size_t)(cbase + c) * NV + n0 + n;
            *(unsigned*)&Sbuf[n * 264 + c] = pk_bf2(x[off], x[off + NV]);
        }
    }
    __syncthreads();

    const int w = t >> 6;        // 0..7
    const int lane = t & 63;
    const int ln = lane & 15;
    const int quad = lane >> 4;
    const int M = m0 + w * 16 + ln;

    f32x4 acc[2] = {};
    const unsigned short* Wrow = &Wp[(size_t)M * 256 + quad * 8];
    for (int k0 = 0; k0 < 256; k0 += 32) {
        short8 a = *(const short8*)&Wrow[k0];
        short8 b[2];
#pragma unroll
        for (int nt = 0; nt < 2; ++nt)
            b[nt] = *(const short8*)&Sbuf[(nt * 16 + ln) * 264 + k0 + quad * 8];
        if (which == 2) {
#pragma unroll
            for (int nt = 0; nt < 2; ++nt)
                acc[nt] = __builtin_amdgcn_mfma_f32_16x16x32_bf16(
                    b[nt], a, acc[nt], 0, 0, 0);
        } else {
#pragma unroll
            for (int nt = 0; nt < 2; ++nt)
                acc[nt] = __builtin_amdgcn_mfma_f32_16x16x32_bf16(
                    a, b[nt], acc[nt], 0, 0, 0);
        }
    }
    __syncthreads();  // Xs no longer needed; reuse Sbuf

    if (which == 2) {
        // lane holds V[n = nt*16+quad*4+r][c' = w*16+ln]; Sbuf[c'][key] pitch 40
        const int cl = w * 16 + ln;            // local channel 0..127
        const float bias = Bp[m0 + cl];
#pragma unroll
        for (int nt = 0; nt < 2; ++nt) {
            unsigned short pk4[4];
#pragma unroll
            for (int r = 0; r < 4; ++r) pk4[r] = f2bf(acc[nt][r] + bias);
            *(uint2*)&Sbuf[cl * 40 + nt * 16 + quad * 4] = *(uint2*)pk4;
        }
        __syncthreads();
        // permuted store: out granule q holds keys {q*4+0..3, 16+q*4+0..3}
        {
            const int cl2 = t >> 2, q = t & 3;
            uint2 lo = *(const uint2*)&Sbuf[cl2 * 40 + q * 4];
            uint2 hi = *(const uint2*)&Sbuf[cl2 * 40 + 16 + q * 4];
            uint4 v;
            v.x = lo.x; v.y = lo.y; v.z = hi.x; v.w = hi.y;
            *(uint4*)&Vbf[(size_t)(m0 + cl2) * NV + n0 + q * 8] = v;
        }
    } else {
        // lane holds D[m = w*16+quad*4+r][n = nt*16+ln]; RoPE, then Et[n][m]
        const int mb = m0 + w * 16 + quad * 4;
        const int cb = mb & 31;
        const float qscale = (which == 0) ? LOG2E : 1.0f;
        float bias[4], invf[4];
#pragma unroll
        for (int r = 0; r < 4; ++r) {
            bias[r] = Bp[mb + r];
            invf[r] = __builtin_amdgcn_exp2f(
                -(float)((cb + r) & 15) * LOG2_10K_16);
        }
        const bool use_sin = (cb < 16);
        const int ml = w * 16 + quad * 4;      // local m 0..127
#pragma unroll
        for (int nt = 0; nt < 2; ++nt) {
            const int n = n0 + nt * 16 + ln;
            const float pos = (float)n * (2.0f / 4095.0f) - 1.0f;
#pragma unroll
            for (int r = 0; r < 4; ++r) {
                float ang = pos * invf[r];
                float f = (use_sin ? __sinf(ang) : __cosf(ang)) * qscale;
                Sbuf[(nt * 16 + ln) * 264 + ml + r] =
                    f2bf((acc[nt][r] + bias[r]) * f);
            }
        }
        __syncthreads();
        // coalesced store: per head 2KB contiguous runs
        unsigned short* dst = (which == 0) ? Qbf : Kbf;
        const int h0 = m0 >> 5;
        {
            const int hh = t >> 7;             // 0..3
            const int n = (t >> 2) & 31;
            const int cw = t & 3;
            uint4 v = *(const uint4*)&Sbuf[n * 264 + hh * 32 + cw * 8];
            *(uint4*)&dst[((size_t)(h0 + hh) * NV + n0 + n) * HD + cw * 8] = v;
        }
    }
}

// ---------------------------------------------------------------------------
// Kernel 2: attention. bf16 MFMA, split-K(4), register-resident P. K and V
// tiles staged via async global_load_lds (16B), double-buffered.
//
// THIS ROUND:
//  * 128-key tiles, ONE barrier per tile (half the vmcnt(0)+barrier drains;
//    2x compute per drain covers the L2 load latency). Each tile is two
//    independent 64-key sub-tiles in LDS so every global_load_lds dest stays
//    linear (wave-uniform base + lane*16) and all read swizzles from the
//    64-key version carry over unchanged.
//  * XCD pair-clustering remap: all 64 q-blocks of one (head, split) pair
//    share linear_id % 8 -> one XCD; per-XCD K/V working set 4MB -> 512KB,
//    fully L2-resident.
//  * s_setprio(1) around MFMA clusters (T5).
//
// grid (NV/64, NHEAD, NSPLIT), block 256.
// ---------------------------------------------------------------------------
__global__ __launch_bounds__(256, 4) void attn_mfma(
    const unsigned short* __restrict__ Qbf,
    const unsigned short* __restrict__ Kbf,
    const unsigned short* __restrict__ Vbf,
    unsigned short* __restrict__ Opartb, float* __restrict__ Lpart)
{
    // bijective remap: blocks with equal (h,z) share l%8 -> same XCD
    const int l = blockIdx.x + (blockIdx.y << 6) + (blockIdx.z << 9);
    const int pr = l & 31;
    const int h = pr & 7;
    const int z = pr >> 3;
    const int q0 = (l >> 5) * 64;
    const int kbase = z * KSPAN;
    const int t = threadIdx.x;
    const int w = t >> 6;
    const int lane = t & 63;
    const int ln = lane & 15;
    const int quad = lane >> 4;

    // K tile: 2 halves x (64 keys x 32c), row=key (64B, 4 granules,
    //         slot = g ^ (key&3))
    // V tile: 2 halves x (32 c x 64 perm-keys), row=c (128B, 8 granules,
    //         slot = g ^ (c&7))
    __shared__ __align__(16) unsigned short Ks[2 * 4096];
    __shared__ __align__(16) unsigned short Vs[2 * 4096];

    const short8 qa = *(const short8*)
        &Qbf[((size_t)h * NV + q0 + w * 16 + ln) * HD + quad * 8];

    const unsigned short* Kh = Kbf + (size_t)h * NV * HD;
    const unsigned short* Vh = Vbf + (size_t)h * HD * NV;

    // V staging: thread t -> channel t>>3, source granule (t&7)^(c&7)
    const int cv = t >> 3;
    const unsigned short* gsrcV = Vh + (size_t)cv * NV + ((t & 7) ^ (cv & 7)) * 8;
    // K staging: thread t -> key t>>2, source granule (t&3)^(key&3)
    const int kv = t >> 2;
    const unsigned short* gsrcK =
        Kh + (size_t)kv * HD + ((t & 3) ^ (kv & 3)) * 8;

    f32x4 oacc[2] = {};
    f32x4 lacc = {};
    const short vone = (short)0x3F80;
    const short8 vones = {vone, vone, vone, vone, vone, vone, vone, vone};

    // prologue: stage tile 0 (128 keys = 4 loads)
    __builtin_amdgcn_global_load_lds(
        (const __attribute__((address_space(1))) unsigned int*)(gsrcK +
            (size_t)kbase * HD),
        (__attribute__((address_space(3))) unsigned int*)&Ks[t * 8], 16, 0, 0);
    __builtin_amdgcn_global_load_lds(
        (const __attribute__((address_space(1))) unsigned int*)(gsrcK +
            (size_t)(kbase + 64) * HD),
        (__attribute__((address_space(3))) unsigned int*)&Ks[2048 + t * 8],
        16, 0, 0);
    __builtin_amdgcn_global_load_lds(
        (const __attribute__((address_space(1))) unsigned int*)(gsrcV + kbase),
        (__attribute__((address_space(3))) unsigned int*)&Vs[t * 8], 16, 0, 0);
    __builtin_amdgcn_global_load_lds(
        (const __attribute__((address_space(1))) unsigned int*)(gsrcV + kbase +
            64),
        (__attribute__((address_space(3))) unsigned int*)&Vs[2048 + t * 8],
        16, 0, 0);
    __syncthreads();

    const int sgk = (quad ^ (ln & 3)) * 8;       // K-read swizzled granule
    for (int i = 0; i < KSPAN / 128; ++i) {
        const int kb = kbase + i * 128;
        const int buf = (i & 1) * 4096;

        if (i + 1 < KSPAN / 128) {
            const int nb = buf ^ 4096;
            __builtin_amdgcn_global_load_lds(
                (const __attribute__((address_space(1))) unsigned int*)(gsrcK +
                    (size_t)(kb + 128) * HD),
                (__attribute__((address_space(3))) unsigned int*)&Ks[nb + t * 8],
                16, 0, 0);
            __builtin_amdgcn_global_load_lds(
                (const __attribute__((address_space(1))) unsigned int*)(gsrcK +
                    (size_t)(kb + 192) * HD),
                (__attribute__((address_space(3))) unsigned int*)&Ks[nb + 2048 +
                    t * 8],
                16, 0, 0);
            __builtin_amdgcn_global_load_lds(
                (const __attribute__((address_space(1))) unsigned int*)(gsrcV +
                    kb + 128),
                (__attribute__((address_space(3))) unsigned int*)&Vs[nb + t * 8],
                16, 0, 0);
            __builtin_amdgcn_global_load_lds(
                (const __attribute__((address_space(1))) unsigned int*)(gsrcV +
                    kb + 192),
                (__attribute__((address_space(3))) unsigned int*)&Vs[nb + 2048 +
                    t * 8],
                16, 0, 0);
        }

#pragma unroll
        for (int hf = 0; hf < 2; ++hf) {
            const int sb = buf + hf * 2048;

            // S^T: lane holds S'[q=ln][key = kb + hf*64 + 16ct + quad*4 + r]
            f32x4 s[4];
            __builtin_amdgcn_s_setprio(1);
#pragma unroll
            for (int ct = 0; ct < 4; ++ct) {
                const short8 kf = *(const short8*)
                    &Ks[sb + (ct * 16 + ln) * 32 + sgk];
                f32x4 z4 = {0.f, 0.f, 0.f, 0.f};
                s[ct] = __builtin_amdgcn_mfma_f32_16x16x32_bf16(kf, qa, z4,
                                                                0, 0, 0);
            }
            __builtin_amdgcn_s_setprio(0);

            float p[4][4];
#pragma unroll
            for (int ct = 0; ct < 4; ++ct)
#pragma unroll
                for (int r = 0; r < 4; ++r)
                    p[ct][r] = __builtin_amdgcn_exp2f(s[ct][r]);

#pragma unroll
            for (int h2 = 0; h2 < 2; ++h2) {
                short8 pa;
                unsigned* pau = (unsigned*)&pa;
                pau[0] = pk_bf2(p[2 * h2][0], p[2 * h2][1]);
                pau[1] = pk_bf2(p[2 * h2][2], p[2 * h2][3]);
                pau[2] = pk_bf2(p[2 * h2 + 1][0], p[2 * h2 + 1][1]);
                pau[3] = pk_bf2(p[2 * h2 + 1][2], p[2 * h2 + 1][3]);
                __builtin_amdgcn_s_setprio(1);
                // denominators: rowsum(P) with the SAME packed weights
                lacc = __builtin_amdgcn_mfma_f32_16x16x32_bf16(pa, vones, lacc,
                                                               0, 0, 0);
#pragma unroll
                for (int ctile = 0; ctile < 2; ++ctile) {
                    const int cA = ctile * 16 + ln;
                    // permuted V: B-frag = one contiguous (swizzled) 16B read
                    const short8 vb = *(const short8*)
                        &Vs[sb + cA * 64 + (((h2 * 4 + quad) ^ (cA & 7)) * 8)];
                    oacc[ctile] = __builtin_amdgcn_mfma_f32_16x16x32_bf16(
                        pa, vb, oacc[ctile], 0, 0, 0);
                }
                __builtin_amdgcn_s_setprio(0);
            }
        }
        __syncthreads();
    }

    unsigned short* Oz = Opartb + (size_t)z * CIN * NV;
    float* Lz = Lpart + (size_t)z * NHEAD * NV;
    if (ln == 0) {
#pragma unroll
        for (int r = 0; r < 4; ++r)
            Lz[(size_t)h * NV + q0 + w * 16 + quad * 4 + r] = lacc[r];
    }
#pragma unroll
    for (int ctile = 0; ctile < 2; ++ctile) {
        uint2 st;
        st.x = pk_bf2(oacc[ctile][0], oacc[ctile][1]);
        st.y = pk_bf2(oacc[ctile][2], oacc[ctile][3]);
        *(uint2*)&Oz[(size_t)(h * HD + ctile * 16 + ln) * NV + q0 + w * 16 +
                     quad * 4] = st;
    }
}

// ---------------------------------------------------------------------------
// Kernel 3: fused combine + output projection. 512-thread blocks, N=32 x
// M=128, grid (128, 4) = 512 blocks.  Y = (sum_z O_z)/(sum_z l_z) + qf,
// staged bf16 in LDS; out = Wo(bf16) @ Y + bo.
// ---------------------------------------------------------------------------
__global__ __launch_bounds__(512) void out_fused(
    const float* __restrict__ x,
    const unsigned short* __restrict__ Opartb,
    const float* __restrict__ Lpart,
    const unsigned short* __restrict__ Wob, const float* __restrict__ bo,
    float* __restrict__ out)
{
    const int n0 = blockIdx.x * 32;
    const int m0 = blockIdx.y * 128;
    const int t = threadIdx.x;

    __shared__ __align__(16) unsigned short Ys[32 * 264];  // 16.9 KB

    {
        const int n2 = (t & 15) * 2;
        const int grp = t >> 4;                 // 0..31, 8 channels each
        const int h = grp >> 2;                 // head
        const size_t lo = (size_t)h * NV + n0 + n2;
        float l0 = 0.f, l1 = 0.f;
#pragma unroll
        for (int zz = 0; zz < NSPLIT; ++zz) {
            l0 += Lpart[(size_t)zz * NHEAD * NV + lo];
            l1 += Lpart[(size_t)zz * NHEAD * NV + lo + 1];
        }
        const float rl0 = __builtin_amdgcn_rcpf(l0);
        const float rl1 = __builtin_amdgcn_rcpf(l1);
#pragma unroll
        for (int i = 0; i < 8; ++i) {
            const int c = grp * 8 + i;
            size_t off = (size_t)c * NV + n0 + n2;
            float s0 = 0.f, s1 = 0.f;
#pragma unroll
            for (int zz = 0; zz < NSPLIT; ++zz) {
                unsigned o = *(const unsigned*)&Opartb[(size_t)zz * CIN * NV + off];
                s0 += bflo(o);
                s1 += bfhi(o);
            }
            float2 x2 = *(const float2*)&x[off];
            Ys[n2 * 264 + c] = f2bf(s0 * rl0 + x2.x);
            Ys[(n2 + 1) * 264 + c] = f2bf(s1 * rl1 + x2.y);
        }
    }
    __syncthreads();

    const int w = t >> 6;        // 0..7
    const int lane = t & 63;
    const int ln = lane & 15;
    const int quad = lane >> 4;
    const int M = m0 + w * 16 + ln;

    const unsigned short* Wrow = &Wob[(size_t)M * 256 + quad * 8];
    f32x4 acc[2] = {};
    for (int k0 = 0; k0 < 256; k0 += 32) {
        short8 a = *(const short8*)&Wrow[k0];
        short8 b[2];
#pragma unroll
        for (int nt = 0; nt < 2; ++nt)
            b[nt] = *(const short8*)&Ys[(nt * 16 + ln) * 264 + k0 + quad * 8];
#pragma unroll
        for (int nt = 0; nt < 2; ++nt)
            acc[nt] = __builtin_amdgcn_mfma_f32_16x16x32_bf16(
                a, b[nt], acc[nt], 0, 0, 0);
    }

    const int mb = m0 + w * 16 + quad * 4;
    float bias[4];
#pragma unroll
    for (int r = 0; r < 4; ++r) bias[r] = bo[mb + r];
#pragma unroll
    for (int nt = 0; nt < 2; ++nt)
#pragma unroll
        for (int r = 0; r < 4; ++r)
            out[(size_t)(mb + r) * NV + n0 + nt * 16 + ln] =
                acc[nt][r] + bias[r];
}

// ---------------------------------------------------------------------------
extern "C" void kernel_launch(void* const* d_in, const int* in_sizes, int n_in,
                              void* d_out, int out_size, void* d_ws,
                              size_t ws_size, hipStream_t stream)
{
    const float* x  = (const float*)d_in[0];
    const float* wq = (const float*)d_in[1];
    const float* bq = (const float*)d_in[2];
    const float* wk = (const float*)d_in[3];
    const float* bk = (const float*)d_in[4];
    const float* wv = (const float*)d_in[5];
    const float* bv = (const float*)d_in[6];
    const float* wo = (const float*)d_in[7];
    const float* bo = (const float*)d_in[8];
    float* out = (float*)d_out;

    unsigned short* Wb  = (unsigned short*)d_ws;            // 655 KB bf16
    unsigned short* Qbf = Wb + 327680;                      // 2MB
    unsigned short* Kbf = Qbf + (size_t)CIN * NV;           // 2MB
    unsigned short* Vbf = Kbf + (size_t)CIN * NV;           // 2MB
    float* Lpart = (float*)(Vbf + (size_t)CIN * NV);        // 512KB (4 splits)
    unsigned short* Opartb =
        (unsigned short*)(Lpart + NSPLIT * (size_t)NHEAD * NV);  // 8MB

    conv_w<<<dim3(320), 256, 0, stream>>>(wq, wk, wv, wo, Wb);
    qkv_fused<<<dim3(128, 2, 3), 512, 0, stream>>>(
        x, Wb, bq, bk, bv, Qbf, Kbf, Vbf);
    attn_mfma<<<dim3(NV / 64, NHEAD, NSPLIT), 256, 0, stream>>>(
        Qbf, Kbf, Vbf, Opartb, Lpart);
    out_fused<<<dim3(128, 4), 512, 0, stream>>>(
        x, Opartb, Lpart, Wb + 196608, bo, out);
}

// Round 2
// 121.721 us; speedup vs baseline: 1.0042x; 1.0042x over previous
//
#include <hip/hip_runtime.h>
#include <hip/hip_bf16.h>

#define CIN 256
#define NV 4096
#define NHEAD 8
#define HD 32
#define NSPLIT 4
#define KSPAN (NV / NSPLIT)
#define LOG2E 1.44269504088896340736f
#define LOG2_10K_16 0.8304820237218405f  /* log2(10000)/16 */

typedef __attribute__((ext_vector_type(8))) short short8;
typedef __attribute__((ext_vector_type(4))) float f32x4;

static __device__ __forceinline__ unsigned short f2bf(float f) {
    union { float f; unsigned u; } v; v.f = f;
    unsigned r = v.u + 0x7fffu + ((v.u >> 16) & 1u);  // RNE
    return (unsigned short)(r >> 16);
}
// pack two fp32 -> packed bf16 pair (truncating): lo from x0, hi from x1
static __device__ __forceinline__ unsigned pk_bf2(float x0, float x1) {
    return __builtin_amdgcn_perm(__float_as_uint(x1), __float_as_uint(x0),
                                 0x07060302u);
}
static __device__ __forceinline__ float bflo(unsigned u) {
    return __uint_as_float(u << 16);
}
static __device__ __forceinline__ float bfhi(unsigned u) {
    return __uint_as_float(u & 0xffff0000u);
}

// ---------------------------------------------------------------------------
// Kernel 0: convert all weights to bf16 once. Wb = Wq|Wk|Wv|Wo, 327680 elems.
// ---------------------------------------------------------------------------
__global__ __launch_bounds__(256) void conv_w(
    const float* __restrict__ wq, const float* __restrict__ wk,
    const float* __restrict__ wv, const float* __restrict__ wo,
    unsigned short* __restrict__ Wb)
{
    int i = (blockIdx.x * 256 + threadIdx.x) * 4;
    if (i >= 327680) return;
    const float* src;
    int off = i;
    if (i < 65536) { src = wq; }
    else if (i < 131072) { src = wk; off = i - 65536; }
    else if (i < 196608) { src = wv; off = i - 131072; }
    else { src = wo; off = i - 196608; }
    float4 v = *(const float4*)&src[off];
    unsigned short pk[4] = {f2bf(v.x), f2bf(v.y), f2bf(v.z), f2bf(v.w)};
    *(uint2*)&Wb[i] = *(uint2*)pk;
}

// ---------------------------------------------------------------------------
// Kernel 1: QKV projection. 512-thread blocks, N=32 x M=128, grid (128,2,3)
// = 768 blocks (3/CU). x-transpose staged bf16 in LDS once; bf16 MFMA with
// direct Wb fragments; epilogue transposes through LDS -> coalesced stores.
//   Q,K -> [h][n][c] (Q pre-scaled by log2e)
//   V   -> [c][n] with keys PERMUTED within each 32-key half so the attention
//          PV B-fragment is one contiguous 16B LDS read:
//          pos q*8 + g*4 + r  holds key g*16 + q*4 + r   (q,g,r in 4,2,4)
// ---------------------------------------------------------------------------
__global__ __launch_bounds__(512) void qkv_fused(
    const float* __restrict__ x, const unsigned short* __restrict__ Wb,
    const float* __restrict__ bq, const float* __restrict__ bk,
    const float* __restrict__ bv,
    unsigned short* __restrict__ Qbf, unsigned short* __restrict__ Kbf,
    unsigned short* __restrict__ Vbf)
{
    const int which = blockIdx.z;
    const unsigned short* Wp = Wb + (size_t)which * 65536;
    const float* Bp = (which == 0) ? bq : (which == 1) ? bk : bv;
    const int cbase = (which == 0) ? 0 : CIN;

    const int n0 = blockIdx.x * 32;
    const int m0 = blockIdx.y * 128;
    const int t = threadIdx.x;

    __shared__ __align__(16) unsigned short Sbuf[32 * 264];  // 16.9 KB

    // stage x [c][n] fp32 -> Xs[n][c] bf16 (row pitch 264)
    {
        const int n = t & 31, cg = t >> 5;  // 16 groups x 16 channels
#pragma unroll 4
        for (int cc = 0; cc < 16; cc += 2) {
            const int c = cg * 16 + cc;
            size_t off = (size_t)(cbase + c) * NV + n0 + n;
            *(unsigned*)&Sbuf[n * 264 + c] = pk_bf2(x[off], x[off + NV]);
        }
    }
    __syncthreads();

    const int w = t >> 6;        // 0..7
    const int lane = t & 63;
    const int ln = lane & 15;
    const int quad = lane >> 4;
    const int M = m0 + w * 16 + ln;

    f32x4 acc[2] = {};
    const unsigned short* Wrow = &Wp[(size_t)M * 256 + quad * 8];
    for (int k0 = 0; k0 < 256; k0 += 32) {
        short8 a = *(const short8*)&Wrow[k0];
        short8 b[2];
#pragma unroll
        for (int nt = 0; nt < 2; ++nt)
            b[nt] = *(const short8*)&Sbuf[(nt * 16 + ln) * 264 + k0 + quad * 8];
        if (which == 2) {
#pragma unroll
            for (int nt = 0; nt < 2; ++nt)
                acc[nt] = __builtin_amdgcn_mfma_f32_16x16x32_bf16(
                    b[nt], a, acc[nt], 0, 0, 0);
        } else {
#pragma unroll
            for (int nt = 0; nt < 2; ++nt)
                acc[nt] = __builtin_amdgcn_mfma_f32_16x16x32_bf16(
                    a, b[nt], acc[nt], 0, 0, 0);
        }
    }
    __syncthreads();  // Xs no longer needed; reuse Sbuf

    if (which == 2) {
        // lane holds V[n = nt*16+quad*4+r][c' = w*16+ln]; Sbuf[c'][key] pitch 40
        const int cl = w * 16 + ln;            // local channel 0..127
        const float bias = Bp[m0 + cl];
#pragma unroll
        for (int nt = 0; nt < 2; ++nt) {
            unsigned short pk4[4];
#pragma unroll
            for (int r = 0; r < 4; ++r) pk4[r] = f2bf(acc[nt][r] + bias);
            *(uint2*)&Sbuf[cl * 40 + nt * 16 + quad * 4] = *(uint2*)pk4;
        }
        __syncthreads();
        // permuted store: out granule q holds keys {q*4+0..3, 16+q*4+0..3}
        {
            const int cl2 = t >> 2, q = t & 3;
            uint2 lo = *(const uint2*)&Sbuf[cl2 * 40 + q * 4];
            uint2 hi = *(const uint2*)&Sbuf[cl2 * 40 + 16 + q * 4];
            uint4 v;
            v.x = lo.x; v.y = lo.y; v.z = hi.x; v.w = hi.y;
            *(uint4*)&Vbf[(size_t)(m0 + cl2) * NV + n0 + q * 8] = v;
        }
    } else {
        // lane holds D[m = w*16+quad*4+r][n = nt*16+ln]; RoPE, then Et[n][m]
        const int mb = m0 + w * 16 + quad * 4;
        const int cb = mb & 31;
        const float qscale = (which == 0) ? LOG2E : 1.0f;
        float bias[4], invf[4];
#pragma unroll
        for (int r = 0; r < 4; ++r) {
            bias[r] = Bp[mb + r];
            invf[r] = __builtin_amdgcn_exp2f(
                -(float)((cb + r) & 15) * LOG2_10K_16);
        }
        const bool use_sin = (cb < 16);
        const int ml = w * 16 + quad * 4;      // local m 0..127
#pragma unroll
        for (int nt = 0; nt < 2; ++nt) {
            const int n = n0 + nt * 16 + ln;
            const float pos = (float)n * (2.0f / 4095.0f) - 1.0f;
#pragma unroll
            for (int r = 0; r < 4; ++r) {
                float ang = pos * invf[r];
                float f = (use_sin ? __sinf(ang) : __cosf(ang)) * qscale;
                Sbuf[(nt * 16 + ln) * 264 + ml + r] =
                    f2bf((acc[nt][r] + bias[r]) * f);
            }
        }
        __syncthreads();
        // coalesced store: per head 2KB contiguous runs
        unsigned short* dst = (which == 0) ? Qbf : Kbf;
        const int h0 = m0 >> 5;
        {
            const int hh = t >> 7;             // 0..3
            const int n = (t >> 2) & 31;
            const int cw = t & 3;
            uint4 v = *(const uint4*)&Sbuf[n * 264 + hh * 32 + cw * 8];
            *(uint4*)&dst[((size_t)(h0 + hh) * NV + n0 + n) * HD + cw * 8] = v;
        }
    }
}

// ---------------------------------------------------------------------------
// Kernel 2: attention. bf16 MFMA, split-K(4), register-resident P.
//
// THIS ROUND — wave-per-KEY-split (4x LDS-read-traffic cut):
//  * Each wave owns 32 of the 128 keys per tile and computes S for ALL 64
//    queries of the block (Q for 4 q-tiles lives in 16 VGPRs). K/V fragment
//    reads drop from 16 to 4 ds_read_b128 per wave per tile; MFMA / exp /
//    pack counts are unchanged.
//  * Each wave accumulates partial O[64q][32c] (32 VGPRs) + partial l
//    (16 VGPRs); one cross-wave LDS tree-reduction at the end, reusing the
//    dead K/V buffers (once per block).
//  * Staging (global_load_lds 16B, double-buffered 128-key tiles), XCD
//    head-clustering remap, and setprio kept from previous round.
//
// grid (NV/64, NHEAD, NSPLIT), block 256.
// ---------------------------------------------------------------------------
__global__ __launch_bounds__(256, 4) void attn_mfma(
    const unsigned short* __restrict__ Qbf,
    const unsigned short* __restrict__ Kbf,
    const unsigned short* __restrict__ Vbf,
    unsigned short* __restrict__ Opartb, float* __restrict__ Lpart)
{
    // bijective remap: blocks with equal head share l%8 -> same XCD
    const int l = blockIdx.x + (blockIdx.y << 6) + (blockIdx.z << 9);
    const int pr = l & 31;
    const int h = pr & 7;
    const int z = pr >> 3;
    const int q0 = (l >> 5) * 64;
    const int kbase = z * KSPAN;
    const int t = threadIdx.x;
    const int w = t >> 6;
    const int lane = t & 63;
    const int ln = lane & 15;
    const int quad = lane >> 4;

    // Shared: K tiles (2 buf x 2 subtile x 64key x 32c) 16KB,
    //         V tiles (2 buf x 2 subtile x 32c x 64 perm-key) 16KB,
    //         + 1KB lred. O-reduction (32KB) overlays Ks+Vs after the loop.
    __shared__ __align__(16) char Smem[33792];
    unsigned short* Ks = (unsigned short*)Smem;
    unsigned short* Vs = (unsigned short*)(Smem + 16384);

    // Q fragments for all 4 q-tiles (B-operand: col=q=ln, k=ch=quad*8..)
    short8 qa[4];
#pragma unroll
    for (int qt = 0; qt < 4; ++qt)
        qa[qt] = *(const short8*)
            &Qbf[((size_t)h * NV + q0 + qt * 16 + ln) * HD + quad * 8];

    const unsigned short* Kh = Kbf + (size_t)h * NV * HD;
    const unsigned short* Vh = Vbf + (size_t)h * HD * NV;

    // V staging: thread t -> channel t>>3, source granule (t&7)^(c&7)
    const int cv = t >> 3;
    const unsigned short* gsrcV = Vh + (size_t)cv * NV + ((t & 7) ^ (cv & 7)) * 8;
    // K staging: thread t -> key t>>2, source granule (t&3)^(key&3)
    const int kv = t >> 2;
    const unsigned short* gsrcK =
        Kh + (size_t)kv * HD + ((t & 3) ^ (kv & 3)) * 8;

    f32x4 oacc[4][2] = {};
    f32x4 lacc[4] = {};
    const short vone = (short)0x3F80;
    const short8 vones = {vone, vone, vone, vone, vone, vone, vone, vone};

    // prologue: stage tile 0 (128 keys = 4 loads)
    __builtin_amdgcn_global_load_lds(
        (const __attribute__((address_space(1))) unsigned int*)(gsrcK +
            (size_t)kbase * HD),
        (__attribute__((address_space(3))) unsigned int*)&Ks[t * 8], 16, 0, 0);
    __builtin_amdgcn_global_load_lds(
        (const __attribute__((address_space(1))) unsigned int*)(gsrcK +
            (size_t)(kbase + 64) * HD),
        (__attribute__((address_space(3))) unsigned int*)&Ks[2048 + t * 8],
        16, 0, 0);
    __builtin_amdgcn_global_load_lds(
        (const __attribute__((address_space(1))) unsigned int*)(gsrcV + kbase),
        (__attribute__((address_space(3))) unsigned int*)&Vs[t * 8], 16, 0, 0);
    __builtin_amdgcn_global_load_lds(
        (const __attribute__((address_space(1))) unsigned int*)(gsrcV + kbase +
            64),
        (__attribute__((address_space(3))) unsigned int*)&Vs[2048 + t * 8],
        16, 0, 0);
    __syncthreads();

    const int sgk = (quad ^ (ln & 3)) * 8;   // K-read swizzled granule
    const int wsub = (w >> 1) * 2048;        // wave's 64-key sub-tile (shorts)
    const int wh = w & 1;                    // wave's 32-key half of sub-tile

    for (int i = 0; i < KSPAN / 128; ++i) {
        const int kb = kbase + i * 128;
        const int buf = (i & 1) * 4096;

        if (i + 1 < KSPAN / 128) {
            const int nb = buf ^ 4096;
            __builtin_amdgcn_global_load_lds(
                (const __attribute__((address_space(1))) unsigned int*)(gsrcK +
                    (size_t)(kb + 128) * HD),
                (__attribute__((address_space(3))) unsigned int*)&Ks[nb + t * 8],
                16, 0, 0);
            __builtin_amdgcn_global_load_lds(
                (const __attribute__((address_space(1))) unsigned int*)(gsrcK +
                    (size_t)(kb + 192) * HD),
                (__attribute__((address_space(3))) unsigned int*)&Ks[nb + 2048 +
                    t * 8],
                16, 0, 0);
            __builtin_amdgcn_global_load_lds(
                (const __attribute__((address_space(1))) unsigned int*)(gsrcV +
                    kb + 128),
                (__attribute__((address_space(3))) unsigned int*)&Vs[nb + t * 8],
                16, 0, 0);
            __builtin_amdgcn_global_load_lds(
                (const __attribute__((address_space(1))) unsigned int*)(gsrcV +
                    kb + 192),
                (__attribute__((address_space(3))) unsigned int*)&Vs[nb + 2048 +
                    t * 8],
                16, 0, 0);
        }

        // wave's K A-fragments: 16 keys each (kt=0,1), shared across q-tiles
        const unsigned short* Kb = &Ks[buf + wsub];
        const unsigned short* Vb = &Vs[buf + wsub];
        const short8 kf0 = *(const short8*)&Kb[(wh * 32 + ln) * 32 + sgk];
        const short8 kf1 = *(const short8*)&Kb[(wh * 32 + 16 + ln) * 32 + sgk];
        // wave's V B-fragments: 32 keys x 16 channels each (ct=0,1)
        const int cA0 = ln, cA1 = 16 + ln;
        const short8 vb0 = *(const short8*)
            &Vb[cA0 * 64 + (((wh * 4 + quad) ^ (cA0 & 7)) * 8)];
        const short8 vb1 = *(const short8*)
            &Vb[cA1 * 64 + (((wh * 4 + quad) ^ (cA1 & 7)) * 8)];

#pragma unroll
        for (int qt = 0; qt < 4; ++qt) {
            f32x4 z4 = {0.f, 0.f, 0.f, 0.f};
            __builtin_amdgcn_s_setprio(1);
            // S[q=ln][key = wave's 32]: D row = key-within-16, col = q
            f32x4 s0 = __builtin_amdgcn_mfma_f32_16x16x32_bf16(kf0, qa[qt],
                                                               z4, 0, 0, 0);
            f32x4 s1 = __builtin_amdgcn_mfma_f32_16x16x32_bf16(kf1, qa[qt],
                                                               z4, 0, 0, 0);
            __builtin_amdgcn_s_setprio(0);

            float p0[4], p1[4];
#pragma unroll
            for (int r = 0; r < 4; ++r) {
                p0[r] = __builtin_amdgcn_exp2f(s0[r]);
                p1[r] = __builtin_amdgcn_exp2f(s1[r]);
            }
            short8 pa;
            unsigned* pau = (unsigned*)&pa;
            pau[0] = pk_bf2(p0[0], p0[1]);
            pau[1] = pk_bf2(p0[2], p0[3]);
            pau[2] = pk_bf2(p1[0], p1[1]);
            pau[3] = pk_bf2(p1[2], p1[3]);

            __builtin_amdgcn_s_setprio(1);
            lacc[qt] = __builtin_amdgcn_mfma_f32_16x16x32_bf16(pa, vones,
                                                               lacc[qt],
                                                               0, 0, 0);
            oacc[qt][0] = __builtin_amdgcn_mfma_f32_16x16x32_bf16(
                pa, vb0, oacc[qt][0], 0, 0, 0);
            oacc[qt][1] = __builtin_amdgcn_mfma_f32_16x16x32_bf16(
                pa, vb1, oacc[qt][1], 0, 0, 0);
            __builtin_amdgcn_s_setprio(0);
        }
        __syncthreads();
    }

    // ---- cross-wave reduction (K/V buffers are dead; overlay with f32) ----
    float* Ored = (float*)Smem;                 // 4w x 4qt x 2ct x 256 f32
    float* lred = (float*)(Smem + 32768);       // 4w x 4qt x 16 f32
#pragma unroll
    for (int qt = 0; qt < 4; ++qt) {
#pragma unroll
        for (int ct = 0; ct < 2; ++ct)
            *(f32x4*)&Ored[(((w * 4 + qt) * 2 + ct) << 8) + lane * 4] =
                oacc[qt][ct];
        if (ln == 0)
            *(f32x4*)&lred[(w * 4 + qt) * 16 + quad * 4] = lacc[qt];
    }
    __syncthreads();

    f32x4 of0 = {}, of1 = {}, lf = {};
#pragma unroll
    for (int w2 = 0; w2 < 4; ++w2) {
        of0 += *(const f32x4*)&Ored[(((w2 * 4 + w) * 2 + 0) << 8) + lane * 4];
        of1 += *(const f32x4*)&Ored[(((w2 * 4 + w) * 2 + 1) << 8) + lane * 4];
        lf  += *(const f32x4*)&lred[(w2 * 4 + w) * 16 + quad * 4];
    }

    unsigned short* Oz = Opartb + (size_t)z * CIN * NV;
    float* Lz = Lpart + (size_t)z * NHEAD * NV;
    if (ln == 0) {
#pragma unroll
        for (int r = 0; r < 4; ++r)
            Lz[(size_t)h * NV + q0 + w * 16 + quad * 4 + r] = lf[r];
    }
    {
        uint2 st;
        st.x = pk_bf2(of0[0], of0[1]);
        st.y = pk_bf2(of0[2], of0[3]);
        *(uint2*)&Oz[(size_t)(h * HD + ln) * NV + q0 + w * 16 + quad * 4] = st;
        st.x = pk_bf2(of1[0], of1[1]);
        st.y = pk_bf2(of1[2], of1[3]);
        *(uint2*)&Oz[(size_t)(h * HD + 16 + ln) * NV + q0 + w * 16 +
                     quad * 4] = st;
    }
}

// ---------------------------------------------------------------------------
// Kernel 3: fused combine + output projection. 512-thread blocks, N=32 x
// M=128, grid (128, 4) = 512 blocks.  Y = (sum_z O_z)/(sum_z l_z) + qf,
// staged bf16 in LDS; out = Wo(bf16) @ Y + bo.
// ---------------------------------------------------------------------------
__global__ __launch_bounds__(512) void out_fused(
    const float* __restrict__ x,
    const unsigned short* __restrict__ Opartb,
    const float* __restrict__ Lpart,
    const unsigned short* __restrict__ Wob, const float* __restrict__ bo,
    float* __restrict__ out)
{
    const int n0 = blockIdx.x * 32;
    const int m0 = blockIdx.y * 128;
    const int t = threadIdx.x;

    __shared__ __align__(16) unsigned short Ys[32 * 264];  // 16.9 KB

    {
        const int n2 = (t & 15) * 2;
        const int grp = t >> 4;                 // 0..31, 8 channels each
        const int h = grp >> 2;                 // head
        const size_t lo = (size_t)h * NV + n0 + n2;
        float l0 = 0.f, l1 = 0.f;
#pragma unroll
        for (int zz = 0; zz < NSPLIT; ++zz) {
            l0 += Lpart[(size_t)zz * NHEAD * NV + lo];
            l1 += Lpart[(size_t)zz * NHEAD * NV + lo + 1];
        }
        const float rl0 = __builtin_amdgcn_rcpf(l0);
        const float rl1 = __builtin_amdgcn_rcpf(l1);
#pragma unroll
        for (int i = 0; i < 8; ++i) {
            const int c = grp * 8 + i;
            size_t off = (size_t)c * NV + n0 + n2;
            float s0 = 0.f, s1 = 0.f;
#pragma unroll
            for (int zz = 0; zz < NSPLIT; ++zz) {
                unsigned o = *(const unsigned*)&Opartb[(size_t)zz * CIN * NV + off];
                s0 += bflo(o);
                s1 += bfhi(o);
            }
            float2 x2 = *(const float2*)&x[off];
            Ys[n2 * 264 + c] = f2bf(s0 * rl0 + x2.x);
            Ys[(n2 + 1) * 264 + c] = f2bf(s1 * rl1 + x2.y);
        }
    }
    __syncthreads();

    const int w = t >> 6;        // 0..7
    const int lane = t & 63;
    const int ln = lane & 15;
    const int quad = lane >> 4;
    const int M = m0 + w * 16 + ln;

    const unsigned short* Wrow = &Wob[(size_t)M * 256 + quad * 8];
    f32x4 acc[2] = {};
    for (int k0 = 0; k0 < 256; k0 += 32) {
        short8 a = *(const short8*)&Wrow[k0];
        short8 b[2];
#pragma unroll
        for (int nt = 0; nt < 2; ++nt)
            b[nt] = *(const short8*)&Ys[(nt * 16 + ln) * 264 + k0 + quad * 8];
#pragma unroll
        for (int nt = 0; nt < 2; ++nt)
            acc[nt] = __builtin_amdgcn_mfma_f32_16x16x32_bf16(
                a, b[nt], acc[nt], 0, 0, 0);
    }

    const int mb = m0 + w * 16 + quad * 4;
    float bias[4];
#pragma unroll
    for (int r = 0; r < 4; ++r) bias[r] = bo[mb + r];
#pragma unroll
    for (int nt = 0; nt < 2; ++nt)
#pragma unroll
        for (int r = 0; r < 4; ++r)
            out[(size_t)(mb + r) * NV + n0 + nt * 16 + ln] =
                acc[nt][r] + bias[r];
}

// ---------------------------------------------------------------------------
extern "C" void kernel_launch(void* const* d_in, const int* in_sizes, int n_in,
                              void* d_out, int out_size, void* d_ws,
                              size_t ws_size, hipStream_t stream)
{
    const float* x  = (const float*)d_in[0];
    const float* wq = (const float*)d_in[1];
    const float* bq = (const float*)d_in[2];
    const float* wk = (const float*)d_in[3];
    const float* bk = (const float*)d_in[4];
    const float* wv = (const float*)d_in[5];
    const float* bv = (const float*)d_in[6];
    const float* wo = (const float*)d_in[7];
    const float* bo = (const float*)d_in[8];
    float* out = (float*)d_out;

    unsigned short* Wb  = (unsigned short*)d_ws;            // 655 KB bf16
    unsigned short* Qbf = Wb + 327680;                      // 2MB
    unsigned short* Kbf = Qbf + (size_t)CIN * NV;           // 2MB
    unsigned short* Vbf = Kbf + (size_t)CIN * NV;           // 2MB
    float* Lpart = (float*)(Vbf + (size_t)CIN * NV);        // 512KB (4 splits)
    unsigned short* Opartb =
        (unsigned short*)(Lpart + NSPLIT * (size_t)NHEAD * NV);  // 8MB

    conv_w<<<dim3(320), 256, 0, stream>>>(wq, wk, wv, wo, Wb);
    qkv_fused<<<dim3(128, 2, 3), 512, 0, stream>>>(
        x, Wb, bq, bk, bv, Qbf, Kbf, Vbf);
    attn_mfma<<<dim3(NV / 64, NHEAD, NSPLIT), 256, 0, stream>>>(
        Qbf, Kbf, Vbf, Opartb, Lpart);
    out_fused<<<dim3(128, 4), 512, 0, stream>>>(
        x, Opartb, Lpart, Wb + 196608, bo, out);
}

// Round 3
// 120.062 us; speedup vs baseline: 1.0181x; 1.0138x over previous
//
#include <hip/hip_runtime.h>
#include <hip/hip_bf16.h>

#define CIN 256
#define NV 4096
#define NHEAD 8
#define HD 32
#define LOG2E 1.44269504088896340736f
#define LOG2_10K_16 0.8304820237218405f  /* log2(10000)/16 */

typedef __attribute__((ext_vector_type(8))) short short8;
typedef __attribute__((ext_vector_type(4))) float f32x4;

static __device__ __forceinline__ unsigned short f2bf(float f) {
    union { float f; unsigned u; } v; v.f = f;
    unsigned r = v.u + 0x7fffu + ((v.u >> 16) & 1u);  // RNE
    return (unsigned short)(r >> 16);
}
// pack two fp32 -> packed bf16 pair (truncating): lo from x0, hi from x1
static __device__ __forceinline__ unsigned pk_bf2(float x0, float x1) {
    return __builtin_amdgcn_perm(__float_as_uint(x1), __float_as_uint(x0),
                                 0x07060302u);
}
static __device__ __forceinline__ float bflo(unsigned u) {
    return __uint_as_float(u << 16);
}
static __device__ __forceinline__ float bfhi(unsigned u) {
    return __uint_as_float(u & 0xffff0000u);
}

// ---------------------------------------------------------------------------
// Kernel 0: convert all weights to bf16 once. Wb = Wq|Wk|Wv|Wo, 327680 elems.
// ---------------------------------------------------------------------------
__global__ __launch_bounds__(256) void conv_w(
    const float* __restrict__ wq, const float* __restrict__ wk,
    const float* __restrict__ wv, const float* __restrict__ wo,
    unsigned short* __restrict__ Wb)
{
    int i = (blockIdx.x * 256 + threadIdx.x) * 4;
    if (i >= 327680) return;
    const float* src;
    int off = i;
    if (i < 65536) { src = wq; }
    else if (i < 131072) { src = wk; off = i - 65536; }
    else if (i < 196608) { src = wv; off = i - 131072; }
    else { src = wo; off = i - 196608; }
    float4 v = *(const float4*)&src[off];
    unsigned short pk[4] = {f2bf(v.x), f2bf(v.y), f2bf(v.z), f2bf(v.w)};
    *(uint2*)&Wb[i] = *(uint2*)pk;
}

// ---------------------------------------------------------------------------
// Kernel 1: QKV projection. 512-thread blocks, N=32 x M=128, grid (128,2,3)
// = 768 blocks (3/CU). x-transpose staged bf16 in LDS once; bf16 MFMA with
// direct Wb fragments; epilogue transposes through LDS -> coalesced stores.
//   Q,K -> [h][n][c] (Q pre-scaled by log2e)
//   V   -> [c][n] with keys PERMUTED within each 32-key half so the attention
//          PV B-fragment is one contiguous 16B LDS read:
//          pos q*8 + g*4 + r  holds key g*16 + q*4 + r   (q,g,r in 4,2,4)
// ---------------------------------------------------------------------------
__global__ __launch_bounds__(512) void qkv_fused(
    const float* __restrict__ x, const unsigned short* __restrict__ Wb,
    const float* __restrict__ bq, const float* __restrict__ bk,
    const float* __restrict__ bv,
    unsigned short* __restrict__ Qbf, unsigned short* __restrict__ Kbf,
    unsigned short* __restrict__ Vbf)
{
    const int which = blockIdx.z;
    const unsigned short* Wp = Wb + (size_t)which * 65536;
    const float* Bp = (which == 0) ? bq : (which == 1) ? bk : bv;
    const int cbase = (which == 0) ? 0 : CIN;

    const int n0 = blockIdx.x * 32;
    const int m0 = blockIdx.y * 128;
    const int t = threadIdx.x;

    __shared__ __align__(16) unsigned short Sbuf[32 * 264];  // 16.9 KB

    // stage x [c][n] fp32 -> Xs[n][c] bf16 (row pitch 264)
    {
        const int n = t & 31, cg = t >> 5;  // 16 groups x 16 channels
#pragma unroll 4
        for (int cc = 0; cc < 16; cc += 2) {
            const int c = cg * 16 + cc;
            size_t off = (size_t)(cbase + c) * NV + n0 + n;
            *(unsigned*)&Sbuf[n * 264 + c] = pk_bf2(x[off], x[off + NV]);
        }
    }
    __syncthreads();

    const int w = t >> 6;        // 0..7
    const int lane = t & 63;
    const int ln = lane & 15;
    const int quad = lane >> 4;
    const int M = m0 + w * 16 + ln;

    f32x4 acc[2] = {};
    const unsigned short* Wrow = &Wp[(size_t)M * 256 + quad * 8];
    for (int k0 = 0; k0 < 256; k0 += 32) {
        short8 a = *(const short8*)&Wrow[k0];
        short8 b[2];
#pragma unroll
        for (int nt = 0; nt < 2; ++nt)
            b[nt] = *(const short8*)&Sbuf[(nt * 16 + ln) * 264 + k0 + quad * 8];
        if (which == 2) {
#pragma unroll
            for (int nt = 0; nt < 2; ++nt)
                acc[nt] = __builtin_amdgcn_mfma_f32_16x16x32_bf16(
                    b[nt], a, acc[nt], 0, 0, 0);
        } else {
#pragma unroll
            for (int nt = 0; nt < 2; ++nt)
                acc[nt] = __builtin_amdgcn_mfma_f32_16x16x32_bf16(
                    a, b[nt], acc[nt], 0, 0, 0);
        }
    }
    __syncthreads();  // Xs no longer needed; reuse Sbuf

    if (which == 2) {
        // lane holds V[n = nt*16+quad*4+r][c' = w*16+ln]; Sbuf[c'][key] pitch 40
        const int cl = w * 16 + ln;            // local channel 0..127
        const float bias = Bp[m0 + cl];
#pragma unroll
        for (int nt = 0; nt < 2; ++nt) {
            unsigned short pk4[4];
#pragma unroll
            for (int r = 0; r < 4; ++r) pk4[r] = f2bf(acc[nt][r] + bias);
            *(uint2*)&Sbuf[cl * 40 + nt * 16 + quad * 4] = *(uint2*)pk4;
        }
        __syncthreads();
        // permuted store: out granule q holds keys {q*4+0..3, 16+q*4+0..3}
        {
            const int cl2 = t >> 2, q = t & 3;
            uint2 lo = *(const uint2*)&Sbuf[cl2 * 40 + q * 4];
            uint2 hi = *(const uint2*)&Sbuf[cl2 * 40 + 16 + q * 4];
            uint4 v;
            v.x = lo.x; v.y = lo.y; v.z = hi.x; v.w = hi.y;
            *(uint4*)&Vbf[(size_t)(m0 + cl2) * NV + n0 + q * 8] = v;
        }
    } else {
        // lane holds D[m = w*16+quad*4+r][n = nt*16+ln]; RoPE, then Et[n][m]
        const int mb = m0 + w * 16 + quad * 4;
        const int cb = mb & 31;
        const float qscale = (which == 0) ? LOG2E : 1.0f;
        float bias[4], invf[4];
#pragma unroll
        for (int r = 0; r < 4; ++r) {
            bias[r] = Bp[mb + r];
            invf[r] = __builtin_amdgcn_exp2f(
                -(float)((cb + r) & 15) * LOG2_10K_16);
        }
        const bool use_sin = (cb < 16);
        const int ml = w * 16 + quad * 4;      // local m 0..127
#pragma unroll
        for (int nt = 0; nt < 2; ++nt) {
            const int n = n0 + nt * 16 + ln;
            const float pos = (float)n * (2.0f / 4095.0f) - 1.0f;
#pragma unroll
            for (int r = 0; r < 4; ++r) {
                float ang = pos * invf[r];
                float f = (use_sin ? __sinf(ang) : __cosf(ang)) * qscale;
                Sbuf[(nt * 16 + ln) * 264 + ml + r] =
                    f2bf((acc[nt][r] + bias[r]) * f);
            }
        }
        __syncthreads();
        // coalesced store: per head 2KB contiguous runs
        unsigned short* dst = (which == 0) ? Qbf : Kbf;
        const int h0 = m0 >> 5;
        {
            const int hh = t >> 7;             // 0..3
            const int n = (t >> 2) & 31;
            const int cw = t & 3;
            uint4 v = *(const uint4*)&Sbuf[n * 264 + hh * 32 + cw * 8];
            *(uint4*)&dst[((size_t)(h0 + hh) * NV + n0 + n) * HD + cw * 8] = v;
        }
    }
}

// ---------------------------------------------------------------------------
// Kernel 2: attention, NO split-K. Each block owns 64 queries of one head and
// streams ALL 4096 keys (32 double-buffered 128-key tiles). Wave-per-key-
// split (each wave owns 32 keys/tile, all 64 queries). Epilogue: cross-wave
// reduction through LDS, divide by the ones-MFMA denominator, and write the
// FINAL attention output Y = O/l as bf16 [c][n]. Removes the 16 MB
// Opart/Lpart round-trip and the combine pass entirely.
// grid (NV/64, NHEAD) = 512 blocks, block 256. Head-clustered: dispatch
// index % 8 == head -> each XCD streams one head's 512 KB K/V from its L2.
// ---------------------------------------------------------------------------
__global__ __launch_bounds__(256, 4) void attn_mfma(
    const unsigned short* __restrict__ Qbf,
    const unsigned short* __restrict__ Kbf,
    const unsigned short* __restrict__ Vbf,
    unsigned short* __restrict__ Ybf)
{
    const int l = blockIdx.x + (blockIdx.y << 6);  // 0..511, dispatch order
    const int h = l & 7;                           // head == l % 8 -> XCD
    const int q0 = (l >> 3) * 64;
    const int t = threadIdx.x;
    const int w = t >> 6;
    const int lane = t & 63;
    const int ln = lane & 15;
    const int quad = lane >> 4;

    // Shared: K tiles (2 buf x 2 subtile x 64key x 32c) 16KB,
    //         V tiles (2 buf x 2 subtile x 32c x 64 perm-key) 16KB,
    //         + 1KB lred. O-reduction (32KB) overlays Ks+Vs after the loop.
    __shared__ __align__(16) char Smem[33792];
    unsigned short* Ks = (unsigned short*)Smem;
    unsigned short* Vs = (unsigned short*)(Smem + 16384);

    // Q fragments for all 4 q-tiles (B-operand: col=q=ln, k=ch=quad*8..)
    short8 qa[4];
#pragma unroll
    for (int qt = 0; qt < 4; ++qt)
        qa[qt] = *(const short8*)
            &Qbf[((size_t)h * NV + q0 + qt * 16 + ln) * HD + quad * 8];

    const unsigned short* Kh = Kbf + (size_t)h * NV * HD;
    const unsigned short* Vh = Vbf + (size_t)h * HD * NV;

    // V staging: thread t -> channel t>>3, source granule (t&7)^(c&7)
    const int cv = t >> 3;
    const unsigned short* gsrcV = Vh + (size_t)cv * NV + ((t & 7) ^ (cv & 7)) * 8;
    // K staging: thread t -> key t>>2, source granule (t&3)^(key&3)
    const int kv = t >> 2;
    const unsigned short* gsrcK =
        Kh + (size_t)kv * HD + ((t & 3) ^ (kv & 3)) * 8;

    f32x4 oacc[4][2] = {};
    f32x4 lacc[4] = {};
    const short vone = (short)0x3F80;
    const short8 vones = {vone, vone, vone, vone, vone, vone, vone, vone};

    // prologue: stage tile 0 (128 keys = 4 loads)
    __builtin_amdgcn_global_load_lds(
        (const __attribute__((address_space(1))) unsigned int*)gsrcK,
        (__attribute__((address_space(3))) unsigned int*)&Ks[t * 8], 16, 0, 0);
    __builtin_amdgcn_global_load_lds(
        (const __attribute__((address_space(1))) unsigned int*)(gsrcK +
            (size_t)64 * HD),
        (__attribute__((address_space(3))) unsigned int*)&Ks[2048 + t * 8],
        16, 0, 0);
    __builtin_amdgcn_global_load_lds(
        (const __attribute__((address_space(1))) unsigned int*)gsrcV,
        (__attribute__((address_space(3))) unsigned int*)&Vs[t * 8], 16, 0, 0);
    __builtin_amdgcn_global_load_lds(
        (const __attribute__((address_space(1))) unsigned int*)(gsrcV + 64),
        (__attribute__((address_space(3))) unsigned int*)&Vs[2048 + t * 8],
        16, 0, 0);
    __syncthreads();

    const int sgk = (quad ^ (ln & 3)) * 8;   // K-read swizzled granule
    const int wsub = (w >> 1) * 2048;        // wave's 64-key sub-tile (shorts)
    const int wh = w & 1;                    // wave's 32-key half of sub-tile

    for (int i = 0; i < NV / 128; ++i) {
        const int kb = i * 128;
        const int buf = (i & 1) * 4096;

        if (i + 1 < NV / 128) {
            const int nb = buf ^ 4096;
            __builtin_amdgcn_global_load_lds(
                (const __attribute__((address_space(1))) unsigned int*)(gsrcK +
                    (size_t)(kb + 128) * HD),
                (__attribute__((address_space(3))) unsigned int*)&Ks[nb + t * 8],
                16, 0, 0);
            __builtin_amdgcn_global_load_lds(
                (const __attribute__((address_space(1))) unsigned int*)(gsrcK +
                    (size_t)(kb + 192) * HD),
                (__attribute__((address_space(3))) unsigned int*)&Ks[nb + 2048 +
                    t * 8],
                16, 0, 0);
            __builtin_amdgcn_global_load_lds(
                (const __attribute__((address_space(1))) unsigned int*)(gsrcV +
                    kb + 128),
                (__attribute__((address_space(3))) unsigned int*)&Vs[nb + t * 8],
                16, 0, 0);
            __builtin_amdgcn_global_load_lds(
                (const __attribute__((address_space(1))) unsigned int*)(gsrcV +
                    kb + 192),
                (__attribute__((address_space(3))) unsigned int*)&Vs[nb + 2048 +
                    t * 8],
                16, 0, 0);
        }

        // wave's K A-fragments: 16 keys each (kt=0,1), shared across q-tiles
        const unsigned short* Kb = &Ks[buf + wsub];
        const unsigned short* Vb = &Vs[buf + wsub];
        const short8 kf0 = *(const short8*)&Kb[(wh * 32 + ln) * 32 + sgk];
        const short8 kf1 = *(const short8*)&Kb[(wh * 32 + 16 + ln) * 32 + sgk];
        // wave's V B-fragments: 32 keys x 16 channels each (ct=0,1)
        const int cA0 = ln, cA1 = 16 + ln;
        const short8 vb0 = *(const short8*)
            &Vb[cA0 * 64 + (((wh * 4 + quad) ^ (cA0 & 7)) * 8)];
        const short8 vb1 = *(const short8*)
            &Vb[cA1 * 64 + (((wh * 4 + quad) ^ (cA1 & 7)) * 8)];

#pragma unroll
        for (int qt = 0; qt < 4; ++qt) {
            f32x4 z4 = {0.f, 0.f, 0.f, 0.f};
            __builtin_amdgcn_s_setprio(1);
            // S[q=ln][key = wave's 32]: D row = key-within-16, col = q
            f32x4 s0 = __builtin_amdgcn_mfma_f32_16x16x32_bf16(kf0, qa[qt],
                                                               z4, 0, 0, 0);
            f32x4 s1 = __builtin_amdgcn_mfma_f32_16x16x32_bf16(kf1, qa[qt],
                                                               z4, 0, 0, 0);
            __builtin_amdgcn_s_setprio(0);

            float p0[4], p1[4];
#pragma unroll
            for (int r = 0; r < 4; ++r) {
                p0[r] = __builtin_amdgcn_exp2f(s0[r]);
                p1[r] = __builtin_amdgcn_exp2f(s1[r]);
            }
            short8 pa;
            unsigned* pau = (unsigned*)&pa;
            pau[0] = pk_bf2(p0[0], p0[1]);
            pau[1] = pk_bf2(p0[2], p0[3]);
            pau[2] = pk_bf2(p1[0], p1[1]);
            pau[3] = pk_bf2(p1[2], p1[3]);

            __builtin_amdgcn_s_setprio(1);
            lacc[qt] = __builtin_amdgcn_mfma_f32_16x16x32_bf16(pa, vones,
                                                               lacc[qt],
                                                               0, 0, 0);
            oacc[qt][0] = __builtin_amdgcn_mfma_f32_16x16x32_bf16(
                pa, vb0, oacc[qt][0], 0, 0, 0);
            oacc[qt][1] = __builtin_amdgcn_mfma_f32_16x16x32_bf16(
                pa, vb1, oacc[qt][1], 0, 0, 0);
            __builtin_amdgcn_s_setprio(0);
        }
        __syncthreads();
    }

    // ---- cross-wave reduction (K/V buffers are dead; overlay with f32) ----
    float* Ored = (float*)Smem;                 // 4w x 4qt x 2ct x 256 f32
    float* lred = (float*)(Smem + 32768);       // 4w x 4qt x 16 f32
#pragma unroll
    for (int qt = 0; qt < 4; ++qt) {
#pragma unroll
        for (int ct = 0; ct < 2; ++ct)
            *(f32x4*)&Ored[(((w * 4 + qt) * 2 + ct) << 8) + lane * 4] =
                oacc[qt][ct];
        if (ln == 0)
            *(f32x4*)&lred[(w * 4 + qt) * 16 + quad * 4] = lacc[qt];
    }
    __syncthreads();

    f32x4 of0 = {}, of1 = {}, lf = {};
#pragma unroll
    for (int w2 = 0; w2 < 4; ++w2) {
        of0 += *(const f32x4*)&Ored[(((w2 * 4 + w) * 2 + 0) << 8) + lane * 4];
        of1 += *(const f32x4*)&Ored[(((w2 * 4 + w) * 2 + 1) << 8) + lane * 4];
        lf  += *(const f32x4*)&lred[(w2 * 4 + w) * 16 + quad * 4];
    }

    // divide by denominator and write FINAL attention output bf16 [c][n]
    float rl[4];
#pragma unroll
    for (int r = 0; r < 4; ++r) rl[r] = __builtin_amdgcn_rcpf(lf[r]);
    {
        uint2 st;
        st.x = pk_bf2(of0[0] * rl[0], of0[1] * rl[1]);
        st.y = pk_bf2(of0[2] * rl[2], of0[3] * rl[3]);
        *(uint2*)&Ybf[(size_t)(h * HD + ln) * NV + q0 + w * 16 + quad * 4] = st;
        st.x = pk_bf2(of1[0] * rl[0], of1[1] * rl[1]);
        st.y = pk_bf2(of1[2] * rl[2], of1[3] * rl[3]);
        *(uint2*)&Ybf[(size_t)(h * HD + 16 + ln) * NV + q0 + w * 16 +
                      quad * 4] = st;
    }
}

// ---------------------------------------------------------------------------
// Kernel 3: output projection. 512-thread blocks, N=32 x M=128, grid (128, 4)
// = 512 blocks. Y_in = attn_out(bf16) + qf, staged bf16 in LDS;
// out = Wo(bf16) @ Y_in + bo.
// ---------------------------------------------------------------------------
__global__ __launch_bounds__(512) void out_fused(
    const float* __restrict__ x,
    const unsigned short* __restrict__ Ybf,
    const unsigned short* __restrict__ Wob, const float* __restrict__ bo,
    float* __restrict__ out)
{
    const int n0 = blockIdx.x * 32;
    const int m0 = blockIdx.y * 128;
    const int t = threadIdx.x;

    __shared__ __align__(16) unsigned short Ys[32 * 264];  // 16.9 KB

    {
        const int n2 = (t & 15) * 2;
        const int grp = t >> 4;                 // 0..31, 8 channels each
#pragma unroll
        for (int i = 0; i < 8; ++i) {
            const int c = grp * 8 + i;
            size_t off = (size_t)c * NV + n0 + n2;
            unsigned o = *(const unsigned*)&Ybf[off];
            float2 x2 = *(const float2*)&x[off];
            Ys[n2 * 264 + c] = f2bf(bflo(o) + x2.x);
            Ys[(n2 + 1) * 264 + c] = f2bf(bfhi(o) + x2.y);
        }
    }
    __syncthreads();

    const int w = t >> 6;        // 0..7
    const int lane = t & 63;
    const int ln = lane & 15;
    const int quad = lane >> 4;
    const int M = m0 + w * 16 + ln;

    const unsigned short* Wrow = &Wob[(size_t)M * 256 + quad * 8];
    f32x4 acc[2] = {};
    for (int k0 = 0; k0 < 256; k0 += 32) {
        short8 a = *(const short8*)&Wrow[k0];
        short8 b[2];
#pragma unroll
        for (int nt = 0; nt < 2; ++nt)
            b[nt] = *(const short8*)&Ys[(nt * 16 + ln) * 264 + k0 + quad * 8];
#pragma unroll
        for (int nt = 0; nt < 2; ++nt)
            acc[nt] = __builtin_amdgcn_mfma_f32_16x16x32_bf16(
                a, b[nt], acc[nt], 0, 0, 0);
    }

    const int mb = m0 + w * 16 + quad * 4;
    float bias[4];
#pragma unroll
    for (int r = 0; r < 4; ++r) bias[r] = bo[mb + r];
#pragma unroll
    for (int nt = 0; nt < 2; ++nt)
#pragma unroll
        for (int r = 0; r < 4; ++r)
            out[(size_t)(mb + r) * NV + n0 + nt * 16 + ln] =
                acc[nt][r] + bias[r];
}

// ---------------------------------------------------------------------------
extern "C" void kernel_launch(void* const* d_in, const int* in_sizes, int n_in,
                              void* d_out, int out_size, void* d_ws,
                              size_t ws_size, hipStream_t stream)
{
    const float* x  = (const float*)d_in[0];
    const float* wq = (const float*)d_in[1];
    const float* bq = (const float*)d_in[2];
    const float* wk = (const float*)d_in[3];
    const float* bk = (const float*)d_in[4];
    const float* wv = (const float*)d_in[5];
    const float* bv = (const float*)d_in[6];
    const float* wo = (const float*)d_in[7];
    const float* bo = (const float*)d_in[8];
    float* out = (float*)d_out;

    unsigned short* Wb  = (unsigned short*)d_ws;            // 655 KB bf16
    unsigned short* Qbf = Wb + 327680;                      // 2MB
    unsigned short* Kbf = Qbf + (size_t)CIN * NV;           // 2MB
    unsigned short* Vbf = Kbf + (size_t)CIN * NV;           // 2MB
    unsigned short* Ybf = Vbf + (size_t)CIN * NV;           // 2MB

    conv_w<<<dim3(320), 256, 0, stream>>>(wq, wk, wv, wo, Wb);
    qkv_fused<<<dim3(128, 2, 3), 512, 0, stream>>>(
        x, Wb, bq, bk, bv, Qbf, Kbf, Vbf);
    attn_mfma<<<dim3(NV / 64, NHEAD), 256, 0, stream>>>(
        Qbf, Kbf, Vbf, Ybf);
    out_fused<<<dim3(128, 4), 512, 0, stream>>>(
        x, Ybf, Wb + 196608, bo, out);
}